// Round 11
// baseline (630.376 us; speedup 1.0000x reference)
//
#include <hip/hip_runtime.h>
#include <hip/hip_bf16.h>
#include <stdint.h>

#define IN_SZ 128
#define HID 128
#define OUT_SZ 67
#define SEQ 512
#define BATCH 2048
#define BT 4
#define NTHR 256
#define SB (SEQ * BATCH)   // 1048576

typedef __attribute__((ext_vector_type(4))) float f32x4;
typedef __attribute__((ext_vector_type(8))) short s16x8;
typedef __attribute__((ext_vector_type(8))) __bf16 bf16x8;

static __device__ __forceinline__ unsigned short f2bf(float f) {
  union { float f; uint32_t u; } c; c.f = f;
  uint32_t u = c.u;
  uint32_t r = u + 0x7FFFu + ((u >> 16) & 1u);
  return (unsigned short)(r >> 16);
}
static __device__ __forceinline__ uint32_t pk2bf(float lo, float hi) {
  __hip_bfloat162 h2 = __float22bfloat162_rn(float2{lo, hi});
  union { __hip_bfloat162 h; uint32_t u; } c; c.h = h2;
  return c.u;
}
static __device__ __forceinline__ float fast_tanh(float x) {
  float e = __builtin_amdgcn_exp2f(x * 2.885390081777927f);
  float r = __builtin_amdgcn_rcpf(e + 1.f);
  return __builtin_fmaf(-2.f, r, 1.f);
}
static __device__ __forceinline__ void mfma16(f32x4& c, s16x8 a, s16x8 b) {
  c = __builtin_amdgcn_mfma_f32_16x16x32_bf16(
        __builtin_bit_cast(bf16x8, a), __builtin_bit_cast(bf16x8, b), c, 0, 0, 0);
}
#define KOFF(g, j) (4 * (g) + ((j) & 3) + (((j) >> 2) << 4))

// clobber-free barrier (validated R9/R10): ds_writes ordered by lgkmcnt(0);
// global loads/stores stay in flight across s_barrier (counted vmcnt).
static __device__ __forceinline__ void frag_barrier() {
  asm volatile("s_waitcnt lgkmcnt(0)");
  __builtin_amdgcn_s_barrier();
}

__global__ __launch_bounds__(NTHR, 2) void rnn_kernel(
    const float* __restrict__ x, const float* __restrict__ hidden,
    const float* __restrict__ mask, const float* __restrict__ Wi2h,
    const float* __restrict__ bi2h, const float* __restrict__ Wi2o,
    const float* __restrict__ bi2o, float* __restrict__ Y) {

  __shared__ s16x8 sF[2][8][64];   // [buf][0..3 x kk, 4..7 h kk][lane]; 16 KB

  const int tid = threadIdx.x;
  const int wave = tid >> 6;
  const int lane = tid & 63;
  const int g = lane >> 4;
  const int n16 = lane & 15;
  // chunked XCD swizzle: 512 blocks = 8 XCDs x 64; consecutive data-blocks
  // (4 share each 64B x-line) land on one XCD's L2
  const int bid = ((blockIdx.x & 7) << 6) | (blockIdx.x >> 3);
  const int b0 = bid * BT;

  // ---- Wi2h A-frags for tiles 2w, 2w+1 ----
  s16x8 W0[8], W1[8];
#pragma unroll
  for (int kt = 0; kt < 8; ++kt) {
    const float* wr0 = Wi2h + (size_t)(16 * (2 * wave + 0) + n16) * (IN_SZ + HID);
    const float* wr1 = Wi2h + (size_t)(16 * (2 * wave + 1) + n16) * (IN_SZ + HID);
    s16x8 w8a, w8b;
#pragma unroll
    for (int j = 0; j < 8; ++j) {
      w8a[j] = (short)f2bf(wr0[32 * kt + KOFF(g, j)]);
      w8b[j] = (short)f2bf(wr1[32 * kt + KOFF(g, j)]);
    }
    W0[kt] = w8a; W1[kt] = w8b;
  }

  // ---- i2o frags: wave w -> out-tile w; wave 3 also tile 4 (rows 64..66) ----
  s16x8 wO[4], wO4[4];
#pragma unroll
  for (int kk = 0; kk < 4; ++kk) {
    s16x8 a, b;
#pragma unroll
    for (int j = 0; j < 8; ++j) {
      int m = 16 * wave + n16;
      a[j] = (short)f2bf(Wi2o[(size_t)m * HID + 32 * kk + KOFF(g, j)]);
      int m4 = 64 + n16;
      b[j] = (short)((wave == 3 && m4 < OUT_SZ)
                     ? f2bf(Wi2o[(size_t)m4 * HID + 32 * kk + KOFF(g, j)]) : 0);
    }
    wO[kk] = a; wO4[kk] = b;
  }

  f32x4 bhv0, bhv1, bov, bov4;
#pragma unroll
  for (int r = 0; r < 4; ++r) {
    bhv0[r] = bi2h[16 * (2 * wave + 0) + 4 * g + r];
    bhv1[r] = bi2h[16 * (2 * wave + 1) + 4 * g + r];
    bov[r] = bi2o[16 * wave + 4 * g + r];
    int m4 = 64 + 4 * g + r;
    bov4[r] = (wave == 3 && m4 < OUT_SZ) ? bi2o[m4] : 0.f;
  }

  // ---- loader mapping: thread -> (col lc, rows 2*lrb, 2*lrb+1) ----
  const int lc = tid & 3;
  const int lrb = tid >> 2;                 // 0..63
  const int R0 = 2 * lrb;                   // even absolute row 0..126
  const int skk = R0 >> 5;                  // frag index
  const int r5 = R0 & 31;
  const int sg = (r5 < 16) ? (r5 >> 2) : ((r5 - 16) >> 2);
  const int sq = ((r5 & 2) >> 1) + ((r5 < 16) ? 0 : 2);   // dword slot in b128
  const int slane = (sg << 4) | lc;
  const char* const xB = (const char*)x;
  uint32_t xrb[2];
#pragma unroll
  for (int i = 0; i < 2; ++i)
    xrb[i] = ((uint32_t)(R0 + i) * (uint32_t)SB + (uint32_t)(b0 + lc)) * 4u;

  // ---- stage x_0, h_0 into buf 0 ----
  {
    float v0 = *(const float*)(xB + xrb[0]);
    float v1 = *(const float*)(xB + xrb[1]);
    ((uint32_t*)&sF[0][skk][slane])[sq] = pk2bf(v0, v1);
    uint32_t h0o = (uint32_t)R0 * (uint32_t)BATCH + (uint32_t)(b0 + lc);
    uint32_t h1o = (uint32_t)(R0 + 1) * (uint32_t)BATCH + (uint32_t)(b0 + lc);
    float hv0 = hidden[(size_t)h0o] * mask[(size_t)h0o];
    float hv1 = hidden[(size_t)h1o] * mask[(size_t)h1o];
    ((uint32_t*)&sF[0][4 + skk][slane])[sq] = pk2bf(hv0, hv1);
  }
  // ---- 4 named prefetch buffers (consume-then-overwrite, validated R10) ----
  float xq0[2], xq1[2], xq2[2], xq3[2];
#pragma unroll
  for (int i = 0; i < 2; ++i) {
    xq0[i] = *(const float*)(xB + xrb[i] + 1u * BATCH * 4u);
    xq1[i] = *(const float*)(xB + xrb[i] + 2u * BATCH * 4u);
    xq2[i] = *(const float*)(xB + xrb[i] + 3u * BATCH * 4u);
    xq3[i] = *(const float*)(xB + xrb[i] + 4u * BATCH * 4u);
  }
  frag_barrier();

  const uint32_t ybase = (uint32_t)(16 * wave + 4 * g) * (uint32_t)SB + (uint32_t)(b0 + n16);
  const uint32_t yb4 = (uint32_t)(64 + 4 * g) * (uint32_t)SB + (uint32_t)(b0 + n16);

#define STEP(T, P, XQ)                                                          \
  {                                                                             \
    const int t = (T);                                                          \
    const int pn = (P) ^ 1;                                                     \
    /* 1. stage x_{t+1} frag dword from XQ (loaded 4 steps ago) */              \
    ((uint32_t*)&sF[pn][skk][slane])[sq] = pk2bf(XQ[0], XQ[1]);                 \
    /* 2. reissue loads x_{t+5} into XQ */                                      \
    {                                                                           \
      const uint32_t tn = (uint32_t)((t + 5 > 511) ? 511 : t + 5) * (BATCH * 4u); \
      XQ[0] = *(const float*)(xB + xrb[0] + tn);                                \
      XQ[1] = *(const float*)(xB + xrb[1] + tn);                                \
    }                                                                           \
    /* 3. frags of [x_t ; h_t] from buf P */                                    \
    s16x8 X0 = sF[P][0][lane], X1 = sF[P][1][lane];                             \
    s16x8 X2 = sF[P][2][lane], X3 = sF[P][3][lane];                             \
    s16x8 H0 = sF[P][4][lane], H1 = sF[P][5][lane];                             \
    s16x8 H2 = sF[P][6][lane], H3 = sF[P][7][lane];                             \
    /* 4. i2h: 4 independent chains, depth 4 */                                 \
    f32x4 a = bhv0, a2 = {0.f, 0.f, 0.f, 0.f};                                  \
    f32x4 b = bhv1, b2 = {0.f, 0.f, 0.f, 0.f};                                  \
    mfma16(a, W0[4], H0);  mfma16(a2, W0[5], H1);                               \
    mfma16(b, W1[4], H0);  mfma16(b2, W1[5], H1);                               \
    mfma16(a, W0[6], H2);  mfma16(a2, W0[7], H3);                               \
    mfma16(b, W1[6], H2);  mfma16(b2, W1[7], H3);                               \
    mfma16(a, W0[0], X0);  mfma16(a2, W0[1], X1);                               \
    mfma16(b, W1[0], X0);  mfma16(b2, W1[1], X1);                               \
    mfma16(a, W0[2], X2);  mfma16(a2, W0[3], X3);                               \
    mfma16(b, W1[2], X2);  mfma16(b2, W1[3], X3);                               \
    /* 5. i2o(t-1) */                                                           \
    if (t > 0) {                                                                \
      const uint32_t ty = (uint32_t)(t - 1) * (uint32_t)BATCH;                  \
      f32x4 ao = bov;                                                           \
      mfma16(ao, wO[0], H0); mfma16(ao, wO[1], H1);                             \
      mfma16(ao, wO[2], H2); mfma16(ao, wO[3], H3);                             \
      if (n16 < BT) {                                                           \
        _Pragma("unroll")                                                       \
        for (int r = 0; r < 4; ++r)                                             \
          Y[(size_t)(ybase + (uint32_t)r * SB + ty)] = fmaxf(ao[r], 0.f);       \
      }                                                                         \
      if (wave == 3) {                                                          \
        f32x4 ao4 = bov4;                                                       \
        mfma16(ao4, wO4[0], H0); mfma16(ao4, wO4[1], H1);                       \
        mfma16(ao4, wO4[2], H2); mfma16(ao4, wO4[3], H3);                       \
        if (n16 < BT && g == 0) {                                               \
          _Pragma("unroll")                                                     \
          for (int r = 0; r < 3; ++r)                                           \
            Y[(size_t)(yb4 + (uint32_t)r * SB + ty)] = fmaxf(ao4[r], 0.f);      \
        }                                                                       \
      }                                                                         \
    }                                                                           \
    /* 6. h_{t+1}: tanh; D-frag(tiles 2w,2w+1) == B-frag kk=w */                \
    {                                                                           \
      f32x4 s0 = a + a2, s1 = b + b2;                                           \
      union { s16x8 v; uint32_t d[4]; } u;                                      \
      u.d[0] = pk2bf(fast_tanh(s0[0]), fast_tanh(s0[1]));                       \
      u.d[1] = pk2bf(fast_tanh(s0[2]), fast_tanh(s0[3]));                       \
      u.d[2] = pk2bf(fast_tanh(s1[0]), fast_tanh(s1[1]));                       \
      u.d[3] = pk2bf(fast_tanh(s1[2]), fast_tanh(s1[3]));                       \
      sF[pn][4 + wave][lane] = u.v;                                             \
    }                                                                           \
    frag_barrier();                                                             \
  }

  for (int t4 = 0; t4 < SEQ; t4 += 4) {
    STEP(t4 + 0, 0, xq0);
    STEP(t4 + 1, 1, xq1);
    STEP(t4 + 2, 0, xq2);
    STEP(t4 + 3, 1, xq3);
  }
#undef STEP

  // ---- epilogue: y_511 from h_512 (buf 0) ----
  {
    s16x8 H0 = sF[0][4][lane], H1 = sF[0][5][lane];
    s16x8 H2 = sF[0][6][lane], H3 = sF[0][7][lane];
    const uint32_t ty = 511u * (uint32_t)BATCH;
    f32x4 ao = bov;
    mfma16(ao, wO[0], H0); mfma16(ao, wO[1], H1);
    mfma16(ao, wO[2], H2); mfma16(ao, wO[3], H3);
    if (n16 < BT) {
#pragma unroll
      for (int r = 0; r < 4; ++r)
        Y[(size_t)(ybase + (uint32_t)r * SB + ty)] = fmaxf(ao[r], 0.f);
    }
    if (wave == 3) {
      f32x4 ao4 = bov4;
      mfma16(ao4, wO4[0], H0); mfma16(ao4, wO4[1], H1);
      mfma16(ao4, wO4[2], H2); mfma16(ao4, wO4[3], H3);
      if (n16 < BT && g == 0) {
#pragma unroll
        for (int r = 0; r < 3; ++r)
          Y[(size_t)(yb4 + (uint32_t)r * SB + ty)] = fmaxf(ao4[r], 0.f);
      }
    }
  }
}

extern "C" void kernel_launch(void* const* d_in, const int* in_sizes, int n_in,
                              void* d_out, int out_size, void* d_ws, size_t ws_size,
                              hipStream_t stream) {
  const float* x      = (const float*)d_in[0];
  const float* hidden = (const float*)d_in[1];
  const float* mask   = (const float*)d_in[2];
  const float* Wi2h   = (const float*)d_in[3];
  const float* bi2h   = (const float*)d_in[4];
  const float* Wi2o   = (const float*)d_in[5];
  const float* bi2o   = (const float*)d_in[6];
  float* Y = (float*)d_out;
  (void)in_sizes; (void)n_in; (void)out_size; (void)d_ws; (void)ws_size;
  rnn_kernel<<<dim3(BATCH / BT), dim3(NTHR), 0, stream>>>(
      x, hidden, mask, Wi2h, bi2h, Wi2o, bi2o, Y);
}

// Round 12
// 530.488 us; speedup vs baseline: 1.1883x; 1.1883x over previous
//
#include <hip/hip_runtime.h>
#include <hip/hip_bf16.h>
#include <stdint.h>

#define IN_SZ 128
#define HID 128
#define OUT_SZ 67
#define SEQ 512
#define BATCH 2048
#define BT 8
#define NTHR 512
#define SB (SEQ * BATCH)   // 1048576

typedef __attribute__((ext_vector_type(4))) float f32x4;
typedef __attribute__((ext_vector_type(8))) short s16x8;
typedef __attribute__((ext_vector_type(8))) __bf16 bf16x8;

static __device__ __forceinline__ unsigned short f2bf(float f) {
  union { float f; uint32_t u; } c; c.f = f;
  uint32_t u = c.u;
  uint32_t r = u + 0x7FFFu + ((u >> 16) & 1u);
  return (unsigned short)(r >> 16);
}
static __device__ __forceinline__ uint32_t pk2bf(float lo, float hi) {
  __hip_bfloat162 h2 = __float22bfloat162_rn(float2{lo, hi});
  union { __hip_bfloat162 h; uint32_t u; } c; c.h = h2;
  return c.u;
}
static __device__ __forceinline__ float fast_tanh(float x) {
  float e = __builtin_amdgcn_exp2f(x * 2.885390081777927f);
  float r = __builtin_amdgcn_rcpf(e + 1.f);
  return __builtin_fmaf(-2.f, r, 1.f);
}
static __device__ __forceinline__ void mfma16(f32x4& c, s16x8 a, s16x8 b) {
  c = __builtin_amdgcn_mfma_f32_16x16x32_bf16(
        __builtin_bit_cast(bf16x8, a), __builtin_bit_cast(bf16x8, b), c, 0, 0, 0);
}
#define KOFF(g, j) (4 * (g) + ((j) & 3) + (((j) >> 2) << 4))

// clobber-free barrier (validated R9/R10): ds_writes ordered by lgkmcnt(0);
// global loads/stores stay in flight across s_barrier (counted vmcnt).
static __device__ __forceinline__ void frag_barrier() {
  asm volatile("s_waitcnt lgkmcnt(0)");
  __builtin_amdgcn_s_barrier();
}

__global__ __launch_bounds__(NTHR, 1) void rnn_kernel(
    const float* __restrict__ x, const float* __restrict__ hidden,
    const float* __restrict__ mask, const float* __restrict__ Wi2h,
    const float* __restrict__ bi2h, const float* __restrict__ Wi2o,
    const float* __restrict__ bi2o, float* __restrict__ Y) {

  __shared__ s16x8 sF[2][8][64];   // [buf][0..3 x kk, 4..7 h kk][lane]; 16 KB

  const int tid = threadIdx.x;
  const int wave = tid >> 6;      // 0..7; owns i2h M-tile `wave`
  const int lane = tid & 63;
  const int g = lane >> 4;
  const int n16 = lane & 15;
  const int bid = ((blockIdx.x & 7) << 5) | (blockIdx.x >> 3);  // XCD-chunk swizzle
  const int b0 = bid * BT;

  // ---- Wi2h A-frags for tile `wave` (32 VGPR) ----
  s16x8 W[8];
#pragma unroll
  for (int kt = 0; kt < 8; ++kt) {
    const float* wr = Wi2h + (size_t)(16 * wave + n16) * (IN_SZ + HID);
    s16x8 w8;
#pragma unroll
    for (int j = 0; j < 8; ++j)
      w8[j] = (short)f2bf(wr[32 * kt + KOFF(g, j)]);
    W[kt] = w8;
  }

  // ---- i2o frags: waves 0..4 own out-tile = wave (rows 16w..16w+15) ----
  const bool hasO = (wave < 5);
  s16x8 wO[4];
#pragma unroll
  for (int kk = 0; kk < 4; ++kk) {
    s16x8 a;
#pragma unroll
    for (int j = 0; j < 8; ++j) {
      int m = 16 * wave + n16;
      a[j] = (short)((hasO && m < OUT_SZ)
                     ? f2bf(Wi2o[(size_t)m * HID + 32 * kk + KOFF(g, j)]) : 0);
    }
    wO[kk] = a;
  }

  f32x4 bhv, bov;
#pragma unroll
  for (int r = 0; r < 4; ++r) {
    bhv[r] = bi2h[16 * wave + 4 * g + r];
    int m = 16 * wave + 4 * g + r;
    bov[r] = (hasO && m < OUT_SZ) ? bi2o[m] : 0.f;
  }

  // ---- loader mapping: thread -> (col lc, rows 2*lrb, 2*lrb+1) ----
  const int lc = tid & 7;
  const int lrb = tid >> 3;                 // 0..63
  const int R0 = 2 * lrb;                   // even row 0..126
  const int skk = R0 >> 5;
  const int r5 = R0 & 31;
  const int sg = (r5 < 16) ? (r5 >> 2) : ((r5 - 16) >> 2);
  const int sq = ((r5 & 2) >> 1) + ((r5 < 16) ? 0 : 2);
  const int slane = (sg << 4) | lc;
  const char* const xB = (const char*)x;
  uint32_t xrb[2];
#pragma unroll
  for (int i = 0; i < 2; ++i)
    xrb[i] = ((uint32_t)(R0 + i) * (uint32_t)SB + (uint32_t)(b0 + lc)) * 4u;

  // ---- stage x_0, h_0 into buf 0 ----
  {
    float v0 = *(const float*)(xB + xrb[0]);
    float v1 = *(const float*)(xB + xrb[1]);
    ((uint32_t*)&sF[0][skk][slane])[sq] = pk2bf(v0, v1);
    uint32_t h0o = (uint32_t)R0 * (uint32_t)BATCH + (uint32_t)(b0 + lc);
    uint32_t h1o = (uint32_t)(R0 + 1) * (uint32_t)BATCH + (uint32_t)(b0 + lc);
    float hv0 = hidden[(size_t)h0o] * mask[(size_t)h0o];
    float hv1 = hidden[(size_t)h1o] * mask[(size_t)h1o];
    ((uint32_t*)&sF[0][4 + skk][slane])[sq] = pk2bf(hv0, hv1);
  }
  // ---- 4 named prefetch buffers (consume-then-overwrite, validated R10) ----
  float xq0[2], xq1[2], xq2[2], xq3[2];
#pragma unroll
  for (int i = 0; i < 2; ++i) {
    xq0[i] = *(const float*)(xB + xrb[i] + 1u * BATCH * 4u);
    xq1[i] = *(const float*)(xB + xrb[i] + 2u * BATCH * 4u);
    xq2[i] = *(const float*)(xB + xrb[i] + 3u * BATCH * 4u);
    xq3[i] = *(const float*)(xB + xrb[i] + 4u * BATCH * 4u);
  }
  frag_barrier();

  const uint32_t ybase = (uint32_t)(16 * wave + 4 * g) * (uint32_t)SB + (uint32_t)(b0 + n16);
  // h-frag write target: half (wave&1) of frag wave>>1 (D-frag == B-frag identity)
  uint32_t* const hdst0 = (uint32_t*)&sF[0][4 + (wave >> 1)][lane] + (wave & 1) * 2;
  uint32_t* const hdst1 = (uint32_t*)&sF[1][4 + (wave >> 1)][lane] + (wave & 1) * 2;

#define STEP(T, P, XQ)                                                          \
  {                                                                             \
    const int t = (T);                                                          \
    const int pn = (P) ^ 1;                                                     \
    /* 1. stage x_{t+1} frag dword from XQ (loaded 4 steps ago) */              \
    ((uint32_t*)&sF[pn][skk][slane])[sq] = pk2bf(XQ[0], XQ[1]);                 \
    /* 2. reissue loads x_{t+5} into XQ */                                      \
    {                                                                           \
      const uint32_t tn = (uint32_t)((t + 5 > 511) ? 511 : t + 5) * (BATCH * 4u); \
      XQ[0] = *(const float*)(xB + xrb[0] + tn);                                \
      XQ[1] = *(const float*)(xB + xrb[1] + tn);                                \
    }                                                                           \
    /* 3. frags of [x_t ; h_t] from buf P */                                    \
    s16x8 X0 = sF[P][0][lane], X1 = sF[P][1][lane];                             \
    s16x8 X2 = sF[P][2][lane], X3 = sF[P][3][lane];                             \
    s16x8 H0 = sF[P][4][lane], H1 = sF[P][5][lane];                             \
    s16x8 H2 = sF[P][6][lane], H3 = sF[P][7][lane];                             \
    /* 4. i2h: 2 chains of depth 4 (one M-tile per wave) */                     \
    f32x4 a = bhv, a2 = {0.f, 0.f, 0.f, 0.f};                                   \
    mfma16(a, W[4], H0);  mfma16(a2, W[5], H1);                                 \
    mfma16(a, W[6], H2);  mfma16(a2, W[7], H3);                                 \
    mfma16(a, W[0], X0);  mfma16(a2, W[1], X1);                                 \
    mfma16(a, W[2], X2);  mfma16(a2, W[3], X3);                                 \
    /* 5. i2o(t-1): waves 0..4 */                                               \
    if (hasO && t > 0) {                                                        \
      const uint32_t ty = (uint32_t)(t - 1) * (uint32_t)BATCH;                  \
      f32x4 ao = bov;                                                           \
      mfma16(ao, wO[0], H0); mfma16(ao, wO[1], H1);                             \
      mfma16(ao, wO[2], H2); mfma16(ao, wO[3], H3);                             \
      if (n16 < BT) {                                                           \
        _Pragma("unroll")                                                       \
        for (int r = 0; r < 4; ++r)                                             \
          if (16 * wave + 4 * g + r < OUT_SZ)                                   \
            Y[(size_t)(ybase + (uint32_t)r * SB + ty)] = fmaxf(ao[r], 0.f);     \
      }                                                                         \
    }                                                                           \
    /* 6. h_{t+1}: tanh; write half-frag (b64) via identity */                  \
    {                                                                           \
      f32x4 s0 = a + a2;                                                        \
      uint32_t hp[2];                                                           \
      hp[0] = pk2bf(fast_tanh(s0[0]), fast_tanh(s0[1]));                        \
      hp[1] = pk2bf(fast_tanh(s0[2]), fast_tanh(s0[3]));                        \
      uint32_t* hd = pn ? hdst1 : hdst0;                                        \
      *(uint64_t*)hd = *(uint64_t*)hp;                                          \
    }                                                                           \
    frag_barrier();                                                             \
  }

  for (int t4 = 0; t4 < SEQ; t4 += 4) {
    STEP(t4 + 0, 0, xq0);
    STEP(t4 + 1, 1, xq1);
    STEP(t4 + 2, 0, xq2);
    STEP(t4 + 3, 1, xq3);
  }
#undef STEP

  // ---- epilogue: y_511 from h_512 (buf 0) ----
  if (hasO) {
    s16x8 H0 = sF[0][4][lane], H1 = sF[0][5][lane];
    s16x8 H2 = sF[0][6][lane], H3 = sF[0][7][lane];
    const uint32_t ty = 511u * (uint32_t)BATCH;
    f32x4 ao = bov;
    mfma16(ao, wO[0], H0); mfma16(ao, wO[1], H1);
    mfma16(ao, wO[2], H2); mfma16(ao, wO[3], H3);
    if (n16 < BT) {
#pragma unroll
      for (int r = 0; r < 4; ++r)
        if (16 * wave + 4 * g + r < OUT_SZ)
          Y[(size_t)(ybase + (uint32_t)r * SB + ty)] = fmaxf(ao[r], 0.f);
    }
  }
}

extern "C" void kernel_launch(void* const* d_in, const int* in_sizes, int n_in,
                              void* d_out, int out_size, void* d_ws, size_t ws_size,
                              hipStream_t stream) {
  const float* x      = (const float*)d_in[0];
  const float* hidden = (const float*)d_in[1];
  const float* mask   = (const float*)d_in[2];
  const float* Wi2h   = (const float*)d_in[3];
  const float* bi2h   = (const float*)d_in[4];
  const float* Wi2o   = (const float*)d_in[5];
  const float* bi2o   = (const float*)d_in[6];
  float* Y = (float*)d_out;
  (void)in_sizes; (void)n_in; (void)out_size; (void)d_ws; (void)ws_size;
  rnn_kernel<<<dim3(BATCH / BT), dim3(NTHR), 0, stream>>>(
      x, hidden, mask, Wi2h, bi2h, Wi2o, bi2o, Y);
}